// Round 3
// baseline (768.044 us; speedup 1.0000x reference)
//
#include <hip/hip_runtime.h>

// SpanBasedChunker: semi-Markov CRF log-likelihood. B=32, L=1024, NS=32768, NG=64.
//
// Pipeline (all on `stream`):
//  1) memsetAsync: per-column hash keys+vals (32 MB)
//  2) scatter: hash-insert span scores into per-(b,e) open-addressing tables
//     (dedupe by start s is REQUIRED: expm1(v1)+expm1(v2) != expm1(v1+v2))
//  3) gold: per-batch LDS hash of gold cells; scan spans, accumulate matches -> num[b]
//  4) prep: per column, compact hash -> (s, expm1(v)) pairs (far: s<=e-5),
//     near-diag coeffs nr[1..4], and c = e^d + e^-d - 1 (ALL transcendentals here)
//  5) dp: one wave/batch, LINEAR domain (x = e^{beta-m}, exact 2^-64 rescale):
//       x_i = P + K_i + sum_t nr_t*x_{i-1-t} + x_{i-1}*c_i      (P = sum x_{<i})
//     Serial chain = pure VALU FMAs (meta prefetched to registers).
//     K-reduce pipelined 4-deep: gather(e+4) / xor{1,2} / xor{4,8} / xor{16,32}
//     -> max 2 dependent shuffles per iteration.
//     Column data streams via global_load_lds ring (PD=16), manual
//     s_waitcnt vmcnt(22); in-order vmcnt retirement => cols <= e+4 resident.
//     No __syncthreads in the loop (single wave, in-order DS unit).
//  6) final: out = sum_b (num[b] - den[b])

#define B_   32
#define L_   1024
#define NS_  32768
#define NG_  64
#define CAP_ 128   // hash slots per (b,e) column; unique s<=e count ~Poisson(32)
#define PD_  16    // dp prefetch ring depth (columns)

#define AS1C(p) ((const __attribute__((address_space(1))) void*)(p))
#define AS3(p)  ((__attribute__((address_space(3))) void*)(p))

// ---------------------------------------------------------------- scatter
__global__ void sbc_scatter(const int2* __restrict__ spans,
                            const float* __restrict__ scores,
                            unsigned int* __restrict__ keys,
                            float* __restrict__ vals) {
    int idx = blockIdx.x * blockDim.x + threadIdx.x;
    if (idx >= B_ * NS_) return;
    int b = idx >> 15;                        // NS_ = 2^15
    int2 se = spans[idx];
    int s = se.x, e = se.y;
    if (s > e) return;                        // DP only reads s<=e cells
    float sc = scores[idx];
    size_t col = ((size_t)b << 10) | (unsigned)e;
    unsigned int* kcol = keys + col * CAP_;
    float*        vcol = vals + col * CAP_;
    unsigned int key = (unsigned int)s + 1u;
    int h = s & (CAP_ - 1);
    for (int probe = 0; probe < CAP_; ++probe) {   // bounded: never hangs
        unsigned int old = atomicCAS(&kcol[h], 0u, key);
        if (old == 0u || old == key) { atomicAdd(&vcol[h], sc); break; }
        h = (h + 1) & (CAP_ - 1);
    }
}

// ---------------------------------------------------------------- gold numerator
__global__ void sbc_gold(const int2* __restrict__ spans,
                         const float* __restrict__ scores,
                         const int2* __restrict__ gold,
                         const int* __restrict__ labels,
                         const float* __restrict__ gmask,
                         float* __restrict__ num) {
    const int b = blockIdx.x;
    const int tid = threadIdx.x;
    __shared__ unsigned int hkey[128];
    __shared__ float hval[128];
    __shared__ int slotof[NG_];
    if (tid < 128) { hkey[tid] = 0u; hval[tid] = 0.f; }
    __syncthreads();
    if (tid < NG_) {                           // insert gold cells (64 into 128)
        int2 se = gold[b * NG_ + tid];
        unsigned int cell = ((unsigned)se.x << 10) | (unsigned)se.y;
        unsigned int key = cell + 1u;
        unsigned int h = (cell * 2654435761u) >> 25;   // top 7 bits
        int slot = (int)h;
        for (int p = 0; p < 128; ++p) {        // bounded; empty slot must exist
            unsigned int old = atomicCAS(&hkey[h], 0u, key);
            if (old == 0u || old == key) { slot = (int)h; break; }
            h = (h + 1u) & 127u;
        }
        slotof[tid] = slot;
    }
    __syncthreads();
    for (int idx = tid; idx < NS_; idx += 256) {   // scan ALL spans (incl s>e)
        int gi = b * NS_ + idx;
        int2 se = spans[gi];
        unsigned int cell = ((unsigned)se.x << 10) | (unsigned)se.y;
        unsigned int key = cell + 1u;
        unsigned int h = (cell * 2654435761u) >> 25;
        for (int p = 0; p < 128; ++p) {        // bounded probe
            unsigned int k = hkey[h];
            if (k == 0u) break;                // not a gold cell
            if (k == key) { atomicAdd(&hval[h], scores[gi]); break; }
            h = (h + 1u) & 127u;
        }
    }
    __syncthreads();
    float acc = 0.f;
    if (tid < NG_) {
        int gi = b * NG_ + tid;
        float v = hval[slotof[tid]];
        float sign = 2.f * (float)labels[gi] - 1.f;
        acc = v * gmask[gi] * sign;
    }
    if (tid < 64) {                            // wave 0 holds all NG_ terms
        #pragma unroll
        for (int o = 32; o; o >>= 1) acc += __shfl_xor(acc, o, 64);
        if (tid == 0) num[b] = acc;
    }
}

// ---------------------------------------------------------------- prep
// Grid-stride, one wave per column per step. Compacts hash into far pairs
// (s <= e-5) and 8-float meta = { cnt, c=e^d+e^-d-1, nr1..nr4, 0, 0 }.
__global__ void __launch_bounds__(256) sbc_prep(const unsigned int* __restrict__ keys,
                                                const float* __restrict__ vals,
                                                uint2* __restrict__ pairs,
                                                float* __restrict__ meta) {
    const int wv = threadIdx.x >> 6;
    const int lane = threadIdx.x & 63;
    __shared__ float dnr[4][8];               // per-wave: [0]=diag, [1..4]=near
    const int nwaves = gridDim.x * 4;
    for (int col = blockIdx.x * 4 + wv; col < B_ * L_; col += nwaves) {
        const int e = col & (L_ - 1);
        const unsigned int* kcol = keys + (size_t)col * CAP_;
        const float*        vcol = vals + (size_t)col * CAP_;
        uint2*              pcol = pairs + (size_t)col * CAP_;
        if (lane < 5) dnr[wv][lane] = 0.f;    // single wave owns row: no barrier
        int cnt = 0;
        #pragma unroll
        for (int r = 0; r < 2; ++r) {
            int slot = lane + r * 64;
            unsigned int k = kcol[slot];
            float v = vcol[slot];
            bool occ = (k != 0u);
            int s = (int)k - 1;
            int t = e - s;                     // t>=0 for occupied (s<=e)
            if (occ && t <= 4) atomicAdd(&dnr[wv][t], v);
            bool far = occ && (t >= 5);
            unsigned long long mb = __ballot(far);
            int pos = cnt + (int)__popcll(mb & ((1ull << lane) - 1ull));
            if (far) pcol[pos] = make_uint2((unsigned)s, __float_as_uint(expm1f(v)));
            cnt += (int)__popcll(mb);
        }
        if (lane == 0) {
            float d = dnr[wv][0];
            float* mp = meta + (size_t)col * 8;
            mp[0] = (float)cnt;
            mp[1] = __expf(d) + __expf(-d) - 1.0f;   // d=0 -> exactly 1
            mp[2] = expm1f(dnr[wv][1]); mp[3] = expm1f(dnr[wv][2]);
            mp[4] = expm1f(dnr[wv][3]); mp[5] = expm1f(dnr[wv][4]);
            mp[6] = 0.f; mp[7] = 0.f;
        }
    }
}

// ---------------------------------------------------------------- dp
__global__ void __launch_bounds__(64) sbc_dp(const uint2* __restrict__ pairs,
                                             const float* __restrict__ meta,
                                             const float* __restrict__ tmask,
                                             float* __restrict__ den) {
    const int b = blockIdx.x;
    const int lane = threadIdx.x;
    __shared__ float xs[L_ + 1];
    __shared__ uint4 plds[PD_][64];           // ring: 64 uint4 (=128 pairs)/col
    __shared__ float mlds[PD_][8];

    const uint4* pbase = (const uint4*)(pairs + (size_t)b * L_ * CAP_);
    const float* mbase = meta + (size_t)b * L_ * 8;

    for (int j = lane; j <= L_; j += 64) xs[j] = 0.f;
    if (lane == 0) xs[0] = 1.f;               // x_0 = e^{beta_0} = 1

    // n = round(sum token_mask); loads consumed before the ring starts
    float tm = 0.f;
    for (int t = lane; t < L_; t += 64) tm += tmask[b * L_ + t];
    #pragma unroll
    for (int o = 32; o; o >>= 1) tm += __shfl_xor(tm, o, 64);
    const int n = (int)(tm + 0.5f);

    // prologue: issue ring loads for columns 0..PD_-1 (2 vmcnt ops/column)
    for (int c = 0; c < PD_; ++c) {
        __builtin_amdgcn_global_load_lds(AS1C(pbase + c * 64 + lane), AS3(&plds[c][0]), 16, 0, 0);
        if (lane < 2)
            __builtin_amdgcn_global_load_lds(AS1C(mbase + c * 8 + lane * 4), AS3(&mlds[c][0]), 16, 0, 0);
    }
    // col 0 resident (32-30=2 oldest retired) -> preload meta(0) to registers
    asm volatile("s_waitcnt vmcnt(30)" ::: "memory");
    float4 mA0 = *(const float4*)&mlds[0][0];  // cnt, c, nr1, nr2
    float2 mA1 = *(const float2*)&mlds[0][4];  // nr3, nr4

    float m = 0.f;                             // log-scale from rescales
    float P = 1.f;                             // sum x_0..x_{i-1}
    float xm1 = 1.f, xm2 = 0.f, xm3 = 0.f, xm4 = 0.f, xm5 = 0.f;
    // K pipeline regs: q1=gathered(e+3), q2=thru xor2(e+2), q3=thru xor8(e+1),
    // q4=K(e) finished. All per-lane partials; butterfly completes over 3 iters.
    float q1 = 0.f, q2 = 0.f, q3 = 0.f, q4 = 0.f;
    const float f2l0 = (float)(2 * lane), f2l1 = (float)(2 * lane + 1);
    int sle = 0;                               // slot of col e; slot (sle+k)%PD = col e+k

    for (int i = 1; i <= L_; ++i) {
        const int e = i - 1;
        // issued = 32+2e, retired >= 32+2e-22 = 2(e+5) -> cols <= e+4 resident
        asm volatile("s_waitcnt vmcnt(22)" ::: "memory");

        // ---- K pipeline (off the serial x chain; <=2 dependent shuffles) ----
        float t3 = q3 + __shfl_xor(q3, 16, 64);
        float kq4 = t3 + __shfl_xor(t3, 32, 64);      // K(e+1) finished
        float t2 = q2 + __shfl_xor(q2, 4, 64);
        float kq3 = t2 + __shfl_xor(t2, 8, 64);
        float t1 = q1 + __shfl_xor(q1, 1, 64);
        float kq2 = t1 + __shfl_xor(t1, 2, 64);
        // gather col e+4 (far cells s <= e-1: xs written through e, safe)
        int sl4 = sle + 4; if (sl4 >= PD_) sl4 -= PD_;
        int sl1 = sle + 1; if (sl1 >= PD_) sl1 -= PD_;
        uint4 pk = plds[sl4][lane];
        float cnt4 = mlds[sl4][0];
        float w0 = (f2l0 < cnt4) ? __uint_as_float(pk.y) : 0.f;
        float w1 = (f2l1 < cnt4) ? __uint_as_float(pk.w) : 0.f;
        int   s0 = (f2l0 < cnt4) ? (int)pk.x : 0;     // guarded lanes read xs[0]: broadcast
        int   s1 = (f2l1 < cnt4) ? (int)pk.z : 0;
        float kq1 = w0 * xs[s0] + w1 * xs[s1];

        // ---- serial chain: pure VALU (meta in registers, K(e)=q4 uniform) ----
        float A = P + q4;
        A += mA0.z * xm2 + mA0.w * xm3;
        A += mA1.x * xm4 + mA1.y * xm5;
        float x = fmaf(xm1, mA0.y, A);        // coeff(x_{i-1}) = 1(P) + c = e^d+e^-d
        if (lane == 0) xs[i] = x;
        P += x;

        // meta prefetch for col e+1 (consumed next iter; latency off-chain)
        float4 mB0 = *(const float4*)&mlds[sl1][0];
        float2 mB1 = *(const float2*)&mlds[sl1][4];

        // issue ring loads for col e+PD_ into slot sle (contents fully consumed)
        int cl = e + PD_; if (cl > L_ - 1) cl = L_ - 1;  // clamped dup: never consumed
        asm volatile("" ::: "memory");        // keep ds_reads above the issues
        __builtin_amdgcn_global_load_lds(AS1C(pbase + cl * 64 + lane), AS3(&plds[sle][0]), 16, 0, 0);
        if (lane < 2)
            __builtin_amdgcn_global_load_lds(AS1C(mbase + cl * 8 + lane * 4), AS3(&mlds[sle][0]), 16, 0, 0);

        // rescale (wave-uniform: x_i >= 2*x_{i-1}, monotone; exact power of 2)
        if (x > 0x1p64f) {
            const float sc = 0x1p-64f;
            x *= sc; xm1 *= sc; xm2 *= sc; xm3 *= sc; xm4 *= sc;
            P *= sc; kq1 *= sc; kq2 *= sc; kq3 *= sc; kq4 *= sc;
            m += 44.361419555836498f;         // 64*ln2
            for (int j = lane; j <= i; j += 64) xs[j] *= sc;
        }

        q4 = kq4; q3 = kq3; q2 = kq2; q1 = kq1;
        xm5 = xm4; xm4 = xm3; xm3 = xm2; xm2 = xm1; xm1 = x;
        mA0 = mB0; mA1 = mB1;
        sle = (sle + 1 == PD_) ? 0 : sle + 1;
    }
    if (lane == 0) den[b] = m + logf(xs[n]);  // n=1024 here; xs[n] at final scale
}

// ---------------------------------------------------------------- final
__global__ void sbc_final(const float* __restrict__ num,
                          const float* __restrict__ den,
                          float* __restrict__ out) {
    int lane = threadIdx.x;
    float v = (lane < B_) ? (num[lane] - den[lane]) : 0.f;
    #pragma unroll
    for (int o = 32; o; o >>= 1) v += __shfl_xor(v, o, 64);
    if (lane == 0) out[0] = v;
}

// ---------------------------------------------------------------- launch
extern "C" void kernel_launch(void* const* d_in, const int* in_sizes, int n_in,
                              void* d_out, int out_size, void* d_ws, size_t ws_size,
                              hipStream_t stream) {
    const int2*  spans       = (const int2*)d_in[0];
    const float* span_scores = (const float*)d_in[1];
    const int2*  gold        = (const int2*)d_in[2];
    const int*   glabels     = (const int*)d_in[3];
    // d_in[4] = span_mask: accepted but unused by the reference math
    const float* gmask       = (const float*)d_in[5];
    const float* tmask       = (const float*)d_in[6];
    float* out = (float*)d_out;
    (void)in_sizes; (void)n_in; (void)out_size; (void)ws_size;

    char* ws = (char*)d_ws;
    const size_t keysB  = (size_t)B_ * L_ * CAP_ * 4;   // 16 MB
    const size_t valsB  = keysB;                        // 16 MB
    const size_t pairsB = (size_t)B_ * L_ * CAP_ * 8;   // 32 MB
    const size_t metaB  = (size_t)B_ * L_ * 8 * 4;      //  1 MB
    unsigned int* keys  = (unsigned int*)(ws);
    float*        vals  = (float*)(ws + keysB);
    uint2*        pairs = (uint2*)(ws + keysB + valsB);
    float*        meta  = (float*)(ws + keysB + valsB + pairsB);
    float*        num   = (float*)(ws + keysB + valsB + pairsB + metaB);
    float*        den   = num + B_;

    hipMemsetAsync(keys, 0, keysB + valsB, stream);     // keys+vals contiguous
    sbc_scatter<<<(B_ * NS_) / 256, 256, 0, stream>>>(spans, span_scores, keys, vals);
    sbc_gold<<<B_, 256, 0, stream>>>(spans, span_scores, gold, glabels, gmask, num);
    sbc_prep<<<2048, 256, 0, stream>>>(keys, vals, pairs, meta);
    sbc_dp<<<B_, 64, 0, stream>>>(pairs, meta, tmask, den);
    sbc_final<<<1, 64, 0, stream>>>(num, den, out);
}

// Round 4
// 363.256 us; speedup vs baseline: 2.1143x; 2.1143x over previous
//
#include <hip/hip_runtime.h>

// SpanBasedChunker: semi-Markov CRF log-likelihood. B=32, L=1024, NS=32768, NG=64.
//
// Pipeline (all on `stream`):
//  1) memsetAsync: per-column hash keys+vals (32 MB)
//  2) scatter: hash-insert ALL span scores into per-(b,e) open-addressing tables
//     (dedupe by start s is REQUIRED: expm1(v1)+expm1(v2) != expm1(v1+v2))
//  3) prep: per column, compact hash -> one 1KB record: 4 uint2 of meta
//     {c=e^d+e^-d-1, nr1..nr4} + up to 124 far pairs (s, expm1(v)) zero-filled.
//     ALL transcendentals happen here.
//  4) gold: 2048 direct hash probes -> num[b]  (no span scan)
//  5) dp: one wave/batch, LINEAR domain (x = e^{beta-m}, exact 2^-64 rescale):
//       x_i = P + K_i + sum_t nr_t*x_{i-1-t} + x_{i-1}*c_i      (P = sum x_{<i})
//     REGISTER-staged 8-deep load pipeline (no global_load_lds: compiler emits
//     precise vmcnt waits for register loads; the LDS-ring version serialized
//     at ~1100 cyc/iter on compiler-inserted drains -> 470us, VALUBusy 0.4%).
//     K-reduce via VALU-only DPP row_shr/row_bcast sum (DS pipe freed).
//     No __syncthreads anywhere in the loop (single wave, in-order DS).
//  6) final: out = sum_b (num[b] - den[b])

#define B_   32
#define L_   1024
#define NS_  32768
#define NG_  64
#define CAP_ 128   // hash slots per (b,e) column; entries/col ~Poisson(32)
#define NREC 128   // uint2 records per column: 4 meta + 124 far pairs

// VALU-only wave-64 sum: inclusive row scans then cross-row broadcasts.
// Lane 63 ends with the total; readlane broadcasts it (uniform).
#define DPP_ADD(v, ctrl) \
    ((v) + __int_as_float(__builtin_amdgcn_update_dpp( \
        0, __float_as_int(v), (ctrl), 0xf, 0xf, false)))

__device__ __forceinline__ float wave_sum64(float v) {
    v = DPP_ADD(v, 0x111);   // row_shr:1
    v = DPP_ADD(v, 0x112);   // row_shr:2
    v = DPP_ADD(v, 0x114);   // row_shr:4
    v = DPP_ADD(v, 0x118);   // row_shr:8  -> lanes 15/31/47/63 hold row sums
    v = DPP_ADD(v, 0x142);   // row_bcast:15
    v = DPP_ADD(v, 0x143);   // row_bcast:31 -> lane 63 = total
    return __int_as_float(__builtin_amdgcn_readlane(__float_as_int(v), 63));
}

// ---------------------------------------------------------------- scatter
__global__ void sbc_scatter(const int2* __restrict__ spans,
                            const float* __restrict__ scores,
                            unsigned int* __restrict__ keys,
                            float* __restrict__ vals) {
    int idx = blockIdx.x * blockDim.x + threadIdx.x;
    if (idx >= B_ * NS_) return;
    int b = idx >> 15;                        // NS_ = 2^15
    int2 se = spans[idx];
    float sc = scores[idx];
    size_t col = ((size_t)b << 10) | (unsigned)se.y;
    unsigned int* kcol = keys + col * CAP_;
    float*        vcol = vals + col * CAP_;
    unsigned int key = (unsigned int)se.x + 1u;
    int h = se.x & (CAP_ - 1);
    for (int p = 0; p < CAP_; ++p) {          // bounded: never hangs
        unsigned int old = atomicCAS(&kcol[h], 0u, key);
        if (old == 0u || old == key) { atomicAdd(&vcol[h], sc); break; }
        h = (h + 1) & (CAP_ - 1);
    }
}

// ---------------------------------------------------------------- prep
// One wave per column (grid-stride). Builds the 1KB dp record in LDS, then
// one coalesced 1KB store. Record (uint2[128]):
//   [0]=(c, nr1) [1]=(nr2, nr3) [2]=(nr4, 0) [3]=(0,0) [4..127]=far pairs.
__global__ void __launch_bounds__(256) sbc_prep(const unsigned int* __restrict__ keys,
                                                const float* __restrict__ vals,
                                                uint2* __restrict__ rec) {
    const int wv = threadIdx.x >> 6;
    const int lane = threadIdx.x & 63;
    __shared__ uint2 st[4][NREC];
    __shared__ float dnr[4][8];
    const int step = gridDim.x * 4;
    for (int col = blockIdx.x * 4 + wv; col < B_ * L_; col += step) {
        const int e = col & (L_ - 1);
        const unsigned int* kcol = keys + (size_t)col * CAP_;
        const float*        vcol = vals + (size_t)col * CAP_;
        ((uint4*)st[wv])[lane] = make_uint4(0u, 0u, 0u, 0u);   // zero-fill
        if (lane < 8) dnr[wv][lane] = 0.f;
        int cnt = 0;
        #pragma unroll
        for (int r = 0; r < 2; ++r) {
            int slot = lane + r * 64;
            unsigned int k = kcol[slot];
            float v = vcol[slot];
            bool occ = (k != 0u);
            int s = (int)k - 1;
            int t = e - s;                     // may be <0 (s>e entries: skip)
            if (occ && t >= 0 && t <= 4) atomicAdd(&dnr[wv][t], v);
            bool far = occ && (t >= 5);
            unsigned long long mb = __ballot(far);
            int pos = cnt + (int)__popcll(mb & ((1ull << lane) - 1ull));
            if (far && pos < NREC - 4)
                st[wv][4 + pos] = make_uint2((unsigned)s, __float_as_uint(expm1f(v)));
            cnt += (int)__popcll(mb);
        }
        if (lane == 0) {
            float d = dnr[wv][0];
            st[wv][0] = make_uint2(__float_as_uint(__expf(d) + __expf(-d) - 1.f),
                                   __float_as_uint(expm1f(dnr[wv][1])));
            st[wv][1] = make_uint2(__float_as_uint(expm1f(dnr[wv][2])),
                                   __float_as_uint(expm1f(dnr[wv][3])));
            st[wv][2] = make_uint2(__float_as_uint(expm1f(dnr[wv][4])), 0u);
        }
        // same-wave DS ordering; compiler inserts lgkmcnt before the read
        ((uint4*)(rec + (size_t)col * NREC))[lane] = ((const uint4*)st[wv])[lane];
    }
}

// ---------------------------------------------------------------- gold numerator
// 2048 probes of the scatter hash (scatter inserted ALL spans, incl. s>e).
__global__ void __launch_bounds__(64) sbc_gold(const unsigned int* __restrict__ keys,
                                               const float* __restrict__ vals,
                                               const int2* __restrict__ gold,
                                               const int* __restrict__ labels,
                                               const float* __restrict__ gmask,
                                               float* __restrict__ num) {
    const int b = blockIdx.x;
    const int lane = threadIdx.x;
    const int gi = b * NG_ + lane;
    int2 se = gold[gi];
    const size_t col = ((size_t)b << 10) | (unsigned)se.y;
    const unsigned int* kcol = keys + col * CAP_;
    const float*        vcol = vals + col * CAP_;
    unsigned int key = (unsigned int)se.x + 1u;
    int h = se.x & (CAP_ - 1);
    float v = 0.f;
    for (int p = 0; p < CAP_; ++p) {           // bounded probe
        unsigned int k = kcol[h];
        if (k == key) { v = vcol[h]; break; }
        if (k == 0u) break;                    // miss -> T=0
        h = (h + 1) & (CAP_ - 1);
    }
    float acc = v * gmask[gi] * (2.f * (float)labels[gi] - 1.f);
    #pragma unroll
    for (int o = 32; o; o >>= 1) acc += __shfl_xor(acc, o, 64);
    if (lane == 0) num[b] = acc;
}

// ---------------------------------------------------------------- dp
__global__ void __launch_bounds__(64) sbc_dp(const uint2* __restrict__ rec,
                                             const float* __restrict__ tmask,
                                             float* __restrict__ den) {
    const int b = blockIdx.x;
    const int lane = threadIdx.x;
    __shared__ float xs[L_ + 1];
    const uint4* pb = (const uint4*)rec + (size_t)b * L_ * (NREC / 2);

    if (lane == 0) xs[0] = 1.f;                // x_0 = e^{beta_0} = 1

    float tm = 0.f;
    for (int t = lane; t < L_; t += 64) tm += tmask[b * L_ + t];
    #pragma unroll
    for (int o = 32; o; o >>= 1) tm += __shfl_xor(tm, o, 64);
    int n = (int)(tm + 0.5f);
    n = (n > L_) ? L_ : n;

    // --- register-staged pipeline -------------------------------------
    // pkS[c%8] holds column c's 1KB record slice (per-lane uint4);
    // loaded 8 iterations before its gather use (precise compiler vmcnt).
    // Meta scalars extracted at gather time (col e+4), carried 4 iters.
    float scC[4], sc1[4], sc2[4], sc3[4], sc4[4];
    #pragma unroll
    for (int c = 0; c < 4; ++c) {              // cols 0..3 meta (no far pairs)
        uint4 t = pb[c * 64 + lane];
        scC[c] = __uint_as_float(__builtin_amdgcn_readlane((int)t.x, 0));
        sc1[c] = __uint_as_float(__builtin_amdgcn_readlane((int)t.y, 0));
        sc2[c] = __uint_as_float(__builtin_amdgcn_readlane((int)t.z, 0));
        sc3[c] = __uint_as_float(__builtin_amdgcn_readlane((int)t.w, 0));
        sc4[c] = __uint_as_float(__builtin_amdgcn_readlane((int)t.x, 1));
    }
    uint4 pkS[8];
    #pragma unroll
    for (int k = 0; k < 8; ++k)                // cols 4..11 into slots c%8
        pkS[(4 + k) & 7] = pb[(4 + k) * 64 + lane];

    float gS[4] = {0.f, 0.f, 0.f, 0.f};        // gather partials (cols e+1..e+4)
    float Kcur = 0.f;                          // K(e), finished last iter
    float P = 1.f, m = 0.f;
    float xm1 = 1.f, xm2 = 0.f, xm3 = 0.f, xm4 = 0.f, xm5 = 0.f;
    const bool gl = (lane >= 2);               // lanes 0,1 carry meta, not pairs

    for (int ii = 0; ii < L_; ii += 8) {
        #pragma unroll
        for (int Kc = 0; Kc < 8; ++Kc) {
            const int e = ii + Kc;
            // meta for col e (extracted 4 iters ago; read before overwrite)
            const float mc = scC[Kc & 3], m1 = sc1[Kc & 3], m2 = sc2[Kc & 3],
                        m3 = sc3[Kc & 3], m4 = sc4[Kc & 3];
            // finish K(e+1): VALU-only DPP sum of partials gathered at e-3
            float Knext = wave_sum64(gS[(Kc + 1) & 3]);
            // gather col e+4 (far pairs s <= e-1; xs filled through e)
            uint4 pk = pkS[(Kc + 4) & 7];
            int   s0 = gl ? (int)pk.x : 0;
            int   s1 = gl ? (int)pk.z : 0;
            float w0 = gl ? __uint_as_float(pk.y) : 0.f;
            float w1 = gl ? __uint_as_float(pk.w) : 0.f;
            float p = w0 * xs[s0] + w1 * xs[s1];
            // extract meta of col e+4 into slot Kc&3 (locals already read)
            scC[Kc & 3] = __uint_as_float(__builtin_amdgcn_readlane((int)pk.x, 0));
            sc1[Kc & 3] = __uint_as_float(__builtin_amdgcn_readlane((int)pk.y, 0));
            sc2[Kc & 3] = __uint_as_float(__builtin_amdgcn_readlane((int)pk.z, 0));
            sc3[Kc & 3] = __uint_as_float(__builtin_amdgcn_readlane((int)pk.w, 0));
            sc4[Kc & 3] = __uint_as_float(__builtin_amdgcn_readlane((int)pk.x, 1));
            gS[Kc & 3] = p;
            // refill stage with col e+12 (clamped dup near the end: never used)
            int cl = e + 12; cl = (cl > L_ - 1) ? (L_ - 1) : cl;
            pkS[(Kc + 4) & 7] = pb[cl * 64 + lane];
            // serial chain: pure VALU; coeff(x_{i-1}) = 1(in P) + c = e^d+e^-d
            float A = (P + Kcur) + (m1 * xm2 + m2 * xm3) + (m3 * xm4 + m4 * xm5);
            float x = fmaf(xm1, mc, A);
            if (lane == 0) xs[e + 1] = x;
            P += x;
            // rescale (wave-uniform, monotone growth; exact power of 2)
            if (x > 0x1p64f) {
                const float s_ = 0x1p-64f;
                x *= s_; xm1 *= s_; xm2 *= s_; xm3 *= s_; xm4 *= s_;
                P *= s_; Knext *= s_;
                gS[0] *= s_; gS[1] *= s_; gS[2] *= s_; gS[3] *= s_;
                m += 44.361419555836498f;      // 64*ln2
                for (int j = lane; j <= e + 1; j += 64) xs[j] *= s_;
            }
            xm5 = xm4; xm4 = xm3; xm3 = xm2; xm2 = xm1; xm1 = x;
            Kcur = Knext;
        }
    }
    if (lane == 0) den[b] = m + logf(xs[n]);
}

// ---------------------------------------------------------------- final
__global__ void sbc_final(const float* __restrict__ num,
                          const float* __restrict__ den,
                          float* __restrict__ out) {
    int lane = threadIdx.x;
    float v = (lane < B_) ? (num[lane] - den[lane]) : 0.f;
    #pragma unroll
    for (int o = 32; o; o >>= 1) v += __shfl_xor(v, o, 64);
    if (lane == 0) out[0] = v;
}

// ---------------------------------------------------------------- launch
extern "C" void kernel_launch(void* const* d_in, const int* in_sizes, int n_in,
                              void* d_out, int out_size, void* d_ws, size_t ws_size,
                              hipStream_t stream) {
    const int2*  spans       = (const int2*)d_in[0];
    const float* span_scores = (const float*)d_in[1];
    const int2*  gold        = (const int2*)d_in[2];
    const int*   glabels     = (const int*)d_in[3];
    // d_in[4] = span_mask: accepted but unused by the reference math
    const float* gmask       = (const float*)d_in[5];
    const float* tmask       = (const float*)d_in[6];
    float* out = (float*)d_out;
    (void)in_sizes; (void)n_in; (void)out_size; (void)ws_size;

    char* ws = (char*)d_ws;
    const size_t keysB = (size_t)B_ * L_ * CAP_ * 4;   // 16 MB
    const size_t valsB = keysB;                        // 16 MB
    const size_t recB  = (size_t)B_ * L_ * NREC * 8;   // 32 MB
    unsigned int* keys = (unsigned int*)(ws);
    float*        vals = (float*)(ws + keysB);
    uint2*        recp = (uint2*)(ws + keysB + valsB);
    float*        num  = (float*)(ws + keysB + valsB + recB);
    float*        den  = num + B_;

    hipMemsetAsync(keys, 0, keysB + valsB, stream);    // keys+vals contiguous
    sbc_scatter<<<(B_ * NS_) / 256, 256, 0, stream>>>(spans, span_scores, keys, vals);
    sbc_prep<<<2048, 256, 0, stream>>>(keys, vals, recp);
    sbc_gold<<<B_, 64, 0, stream>>>(keys, vals, gold, glabels, gmask, num);
    sbc_dp<<<B_, 64, 0, stream>>>(recp, tmask, den);
    sbc_final<<<1, 64, 0, stream>>>(num, den, out);
}